// Round 6
// baseline (532.912 us; speedup 1.0000x reference)
//
#include <hip/hip_runtime.h>
#include <hip/hip_bf16.h>

constexpr int NB  = 2;
constexpr int SL  = 2048;
constexpr int EMB = 1024;
constexpr int NH  = 16;
constexpr int HD  = 64;
constexpr int MT  = NB * SL;               // 4096 rows for projection GEMMs
constexpr size_t PROJ = (size_t)MT * EMB;  // 4M elements per [N,L,E] buffer

typedef __attribute__((ext_vector_type(8))) short bf16x8;  // 8 bf16 (4 VGPRs)
typedef __attribute__((ext_vector_type(4))) float f32x4;   // MFMA C/D frag

__device__ inline short f2b(float f) {
  __hip_bfloat16 b = __float2bfloat16(f);
  short s; __builtin_memcpy(&s, &b, 2); return s;
}

#define GLDS16(g, l)                                                     \
  __builtin_amdgcn_global_load_lds(                                      \
      (const __attribute__((address_space(1))) void*)(g),                \
      (__attribute__((address_space(3))) void*)(l), 16, 0, 0)

// ---------------------------------------------------------------------------
// Cast fp32 -> bf16: x -> xb, {Wq,Wk,Wv} -> wqkv (concat rows), Wo -> wob.
// ---------------------------------------------------------------------------
__global__ __launch_bounds__(256) void cast_all(
    const float* __restrict__ x,  const float* __restrict__ wq,
    const float* __restrict__ wk, const float* __restrict__ wv,
    const float* __restrict__ wo, short* __restrict__ xb,
    short* __restrict__ wqkv, short* __restrict__ wob) {
  const size_t t = (size_t)blockIdx.x * 256 + threadIdx.x;  // float4 index
  const float* src; short* dst; size_t base;
  if (t < 1048576)      { src = x;  dst = xb;              base = 0; }
  else if (t < 1310720) { src = wq; dst = wqkv;            base = 1048576; }
  else if (t < 1572864) { src = wk; dst = wqkv + (1 << 20); base = 1310720; }
  else if (t < 1835008) { src = wv; dst = wqkv + (2 << 20); base = 1572864; }
  else                  { src = wo; dst = wob;             base = 1835008; }
  const size_t i = t - base;
  const float4 v = ((const float4*)src)[i];
  const short4 o = {f2b(v.x), f2b(v.y), f2b(v.z), f2b(v.w)};
  ((short4*)dst)[i] = o;
}

// ---------------------------------------------------------------------------
// QKV GEMM (verified): C = x[4096][1024] @ wqkv[3072][1024]^T.
// 128x128 tile, BK=64, grid 24x32 = 768 blocks (3/CU). Involutive 16B-chunk
// XOR swizzle (chunk ^= row&7): linear global_load_lds dest + inverse-
// swizzled per-lane GLOBAL source + swizzled read index (rule #21).
// Epilogue per n-region: 0 -> Q*(log2e/32) row-major; 1 -> K frag-blocked;
// 2 -> V frag-blocked (PV key-permutation folded).
// ---------------------------------------------------------------------------
__global__ __launch_bounds__(256) void gemm_qkv(
    const short* __restrict__ A, const short* __restrict__ W,
    short* __restrict__ qb, short* __restrict__ kb, short* __restrict__ vt) {
  __shared__ short As[128 * 64];
  __shared__ short Bs[128 * 64];
  const int tid = threadIdx.x;
  const int w = tid >> 6, lane = tid & 63;
  const int la = lane >> 4, lb = lane & 15;
  const int wm = w & 1, wn = w >> 1;
  const int m0 = blockIdx.y << 7, n0 = blockIdx.x << 7;
  const int srow = lane >> 3;
  const int scol = ((lane & 7) ^ srow) << 3;  // shorts
  const short* a0 = A + (size_t)(m0 + w * 32 + srow) * 1024 + scol;
  const short* b0 = W + (size_t)(n0 + w * 32 + srow) * 1024 + scol;
  short* lAw = As + (w * 32) * 64;
  short* lBw = Bs + (w * 32) * 64;

  f32x4 acc[4][4];
#pragma unroll
  for (int i = 0; i < 4; ++i)
#pragma unroll
    for (int j = 0; j < 4; ++j) acc[i][j] = (f32x4){0.f, 0.f, 0.f, 0.f};

  for (int k0 = 0; k0 < 1024; k0 += 64) {
    __syncthreads();
#pragma unroll
    for (int g = 0; g < 4; ++g) GLDS16(a0 + g * 8 * 1024 + k0, lAw + g * 8 * 64);
#pragma unroll
    for (int g = 0; g < 4; ++g) GLDS16(b0 + g * 8 * 1024 + k0, lBw + g * 8 * 64);
    __syncthreads();
#pragma unroll
    for (int ks = 0; ks < 2; ++ks) {
      bf16x8 af[4], bfr[4];
#pragma unroll
      for (int i = 0; i < 4; ++i) {
        const int row = wm * 64 + i * 16 + lb;
        af[i] = *(const bf16x8*)&As[row * 64 + (((ks << 2) + la) ^ (row & 7)) * 8];
      }
#pragma unroll
      for (int j = 0; j < 4; ++j) {
        const int row = wn * 64 + j * 16 + lb;
        bfr[j] = *(const bf16x8*)&Bs[row * 64 + (((ks << 2) + la) ^ (row & 7)) * 8];
      }
#pragma unroll
      for (int i = 0; i < 4; ++i)
#pragma unroll
        for (int j = 0; j < 4; ++j)
          acc[i][j] = __builtin_amdgcn_mfma_f32_16x16x32_bf16(af[i], bfr[j],
                                                              acc[i][j], 0, 0, 0);
    }
  }

  const int region = n0 >> 10;  // block-uniform (n-tile 128 < 1024)
  if (region == 0) {
    const float sc = 0.03125f * 1.44269504f;  // 1/sqrt(1024) * log2(e)
#pragma unroll
    for (int j = 0; j < 4; ++j) {
      const int nj = (n0 & 1023) + wn * 64 + j * 16 + lb;
#pragma unroll
      for (int i = 0; i < 4; ++i) {
        const int mi = m0 + wm * 64 + i * 16 + la * 4;
#pragma unroll
        for (int r = 0; r < 4; ++r)
          qb[(size_t)(mi + r) * 1024 + nj] = f2b(acc[i][j][r] * sc);
      }
    }
  } else if (region == 1) {
    // K fragment-blocked
#pragma unroll
    for (int j = 0; j < 4; ++j) {
      const int nj = (n0 & 1023) + wn * 64 + j * 16 + lb;
      const int hh = nj >> 6, d = nj & 63;
      const int ks = d >> 5, Gd = (d >> 3) & 3, jj = d & 7;
#pragma unroll
      for (int i = 0; i < 4; ++i) {
        const int mi = m0 + wm * 64 + i * 16 + la * 4;
        const int nbi = mi >> 11, seq = mi & (SL - 1);
        const size_t base = ((size_t)(nbi * NH + hh) << 17) +
                            (size_t)(seq >> 4) * 1024 + ks * 512 + Gd * 128 +
                            (seq & 15) * 8 + jj;
#pragma unroll
        for (int r = 0; r < 4; ++r) kb[base + r * 8] = f2b(acc[i][j][r]);
      }
    }
  } else {
    // V fragment-blocked (PV key-permutation folded in)
#pragma unroll
    for (int j = 0; j < 4; ++j) {
      const int nv = (n0 - 2048) + wn * 64 + j * 16 + lb;
      const int hh = nv >> 6, d = nv & 63;
      const int mtd = d >> 4, lbv = d & 15;
#pragma unroll
      for (int i = 0; i < 4; ++i) {
        const int mi = m0 + wm * 64 + i * 16 + la * 4;
        const int nbi = mi >> 11, seq = mi & (SL - 1);
        const int kq = seq >> 5, g = (seq >> 2) & 3, hi = (seq >> 4) & 1;
        const short4 o = {f2b(acc[i][j][0]), f2b(acc[i][j][1]),
                          f2b(acc[i][j][2]), f2b(acc[i][j][3])};
        *(short4*)&vt[((size_t)(nbi * NH + hh) << 17) + (size_t)kq * 2048 +
                      mtd * 512 + g * 128 + lbv * 8 + 4 * hi] = o;
      }
    }
  }
}

// ---------------------------------------------------------------------------
// Out GEMM (round-3 verified version): out = ab[4096][1024](bf16) @
// wob[1024][1024]^T + bias, fp32 out. 128m x 64n tile, BK=64, chunk-XOR
// swizzle, grid 16x32 = 512 blocks (2/CU so barrier drains overlap).
// ---------------------------------------------------------------------------
__global__ __launch_bounds__(256) void gemm_out(
    const short* __restrict__ A, const short* __restrict__ W,
    const float* __restrict__ bias, float* __restrict__ out) {
  __shared__ short As[128 * 64];
  __shared__ short Bs[64 * 64];
  const int tid = threadIdx.x;
  const int w = tid >> 6, lane = tid & 63;
  const int la = lane >> 4, lb = lane & 15;
  const int wm = w & 1, wn = w >> 1;
  const int m0 = blockIdx.y << 7, n0 = blockIdx.x << 6;
  const int srow = lane >> 3;
  const int scol = ((lane & 7) ^ srow) << 3;
  const short* a0 = A + (size_t)(m0 + w * 32 + srow) * 1024 + scol;
  const short* b0 = W + (size_t)(n0 + w * 16 + srow) * 1024 + scol;
  short* lAw = As + (w * 32) * 64;
  short* lBw = Bs + (w * 16) * 64;

  f32x4 acc[4][2];
#pragma unroll
  for (int i = 0; i < 4; ++i)
#pragma unroll
    for (int j = 0; j < 2; ++j) acc[i][j] = (f32x4){0.f, 0.f, 0.f, 0.f};

  for (int k0 = 0; k0 < 1024; k0 += 64) {
    __syncthreads();
#pragma unroll
    for (int g = 0; g < 4; ++g) GLDS16(a0 + g * 8 * 1024 + k0, lAw + g * 8 * 64);
#pragma unroll
    for (int g = 0; g < 2; ++g) GLDS16(b0 + g * 8 * 1024 + k0, lBw + g * 8 * 64);
    __syncthreads();
#pragma unroll
    for (int ks = 0; ks < 2; ++ks) {
      bf16x8 af[4], bfr[2];
#pragma unroll
      for (int i = 0; i < 4; ++i) {
        const int row = wm * 64 + i * 16 + lb;
        af[i] = *(const bf16x8*)&As[row * 64 + (((ks << 2) + la) ^ (row & 7)) * 8];
      }
#pragma unroll
      for (int j = 0; j < 2; ++j) {
        const int row = wn * 32 + j * 16 + lb;
        bfr[j] = *(const bf16x8*)&Bs[row * 64 + (((ks << 2) + la) ^ (row & 7)) * 8];
      }
#pragma unroll
      for (int i = 0; i < 4; ++i)
#pragma unroll
        for (int j = 0; j < 2; ++j)
          acc[i][j] = __builtin_amdgcn_mfma_f32_16x16x32_bf16(af[i], bfr[j],
                                                              acc[i][j], 0, 0, 0);
    }
  }
#pragma unroll
  for (int j = 0; j < 2; ++j) {
    const int nj = n0 + wn * 32 + j * 16 + lb;
    const float bv = bias[nj];
#pragma unroll
    for (int i = 0; i < 4; ++i) {
      const int mi = m0 + wm * 64 + i * 16 + la * 4;
#pragma unroll
      for (int r = 0; r < 4; ++r)
        out[(size_t)(mi + r) * 1024 + nj] = acc[i][j][r] + bv;
    }
  }
}

// ---------------------------------------------------------------------------
// Flash attention v10: zero-LDS main loop (direct global->register K/V,
// fragment-blocked layouts) at DOUBLE occupancy.
//  * 512-thread blocks: 8 waves = 2 wq (64 q-rows each) x 4 wk (key split:
//    wave wk owns kb32 blocks {4j+wk}). 512 blocks x 8 waves = 4096 waves
//    = 4 waves/SIMD (was 2) -> MFMA/VALU pipes stay co-fed through the
//    serial QK->exp2/cvt->PV dependency chain.
//  * Same L2 traffic as v9: 8 waves x 1/4 K,V = x2 duplication per block,
//    1 MB/block, unchanged.
//  * __launch_bounds__(512,4): body compiles to exactly 128 VGPR, the
//    4-waves/EU budget -> no spill expected.
//  * Epilogue: 3-step serial LDS add-tree over wk (one f32 buffer/ wq).
// ---------------------------------------------------------------------------
#define LOADK(DK, KB32)                                                      \
  do {                                                                       \
    _Pragma("unroll") for (int rr_ = 0; rr_ < 2; ++rr_)                      \
        _Pragma("unroll") for (int ks_ = 0; ks_ < 2; ++ks_)                  \
            DK[rr_][ks_] = *(const bf16x8*)(Kb + (size_t)(KB32) * 2048 +     \
                                            rr_ * 1024 + ks_ * 512);         \
  } while (0)

#define LOADV(DV, KB32)                                                      \
  do {                                                                       \
    _Pragma("unroll") for (int md_ = 0; md_ < 4; ++md_)                      \
        DV[md_] = *(const bf16x8*)(Vb + (size_t)(KB32) * 2048 + md_ * 512);  \
  } while (0)

#define ATTN_STEP(AK, AV)                                                    \
  do {                                                                       \
    f32x4 S[2][4];                                                           \
    _Pragma("unroll") for (int mt = 0; mt < 2; ++mt)                         \
        _Pragma("unroll") for (int nt = 0; nt < 4; ++nt)                     \
            S[mt][nt] = (f32x4){0.f, 0.f, 0.f, 0.f};                         \
    __builtin_amdgcn_s_setprio(1);                                           \
    _Pragma("unroll") for (int ks = 0; ks < 2; ++ks)                         \
        _Pragma("unroll") for (int nt = 0; nt < 4; ++nt) {                   \
      S[0][nt] = __builtin_amdgcn_mfma_f32_16x16x32_bf16(AK[0][ks],          \
                     bQ[nt][ks], S[0][nt], 0, 0, 0);                         \
      S[1][nt] = __builtin_amdgcn_mfma_f32_16x16x32_bf16(AK[1][ks],          \
                     bQ[nt][ks], S[1][nt], 0, 0, 0);                         \
    }                                                                        \
    __builtin_amdgcn_s_setprio(0);                                           \
    _Pragma("unroll") for (int nt = 0; nt < 4; ++nt) {                       \
      _Pragma("unroll") for (int mt = 0; mt < 2; ++mt)                       \
          _Pragma("unroll") for (int r = 0; r < 4; ++r) {                    \
        const float p = __builtin_amdgcn_exp2f(S[mt][nt][r]);                \
        S[mt][nt][r] = p;                                                    \
        lacc[nt] += p;                                                       \
      }                                                                      \
      bf16x8 B2;                                                             \
      B2[0] = f2b(S[0][nt][0]); B2[1] = f2b(S[0][nt][1]);                    \
      B2[2] = f2b(S[0][nt][2]); B2[3] = f2b(S[0][nt][3]);                    \
      B2[4] = f2b(S[1][nt][0]); B2[5] = f2b(S[1][nt][1]);                    \
      B2[6] = f2b(S[1][nt][2]); B2[7] = f2b(S[1][nt][3]);                    \
      __builtin_amdgcn_s_setprio(1);                                         \
      _Pragma("unroll") for (int mtd = 0; mtd < 4; ++mtd)                    \
          O[mtd][nt] = __builtin_amdgcn_mfma_f32_16x16x32_bf16(              \
              AV[mtd], B2, O[mtd][nt], 0, 0, 0);                             \
      __builtin_amdgcn_s_setprio(0);                                         \
    }                                                                        \
  } while (0)

__global__ __launch_bounds__(512, 4) void attn_mfma(const short* __restrict__ Qg,
                                                    const short* __restrict__ Kp,
                                                    const short* __restrict__ Vp,
                                                    short* __restrict__ Ab) {
  __shared__ __align__(16) float red[2][64][68];  // 34816 B
  __shared__ float lred[2][64];
  const int tid = threadIdx.x;
  const int w = tid >> 6, lane = tid & 63;
  const int G = lane >> 4, lb = lane & 15;
  const int wk = w & 3, wq = w >> 2;
  const int h = blockIdx.x, qt = blockIdx.y, n = blockIdx.z;

  // ---- Q fragments: global -> regs, once. q = 64wq+16nt+lb, d = 32ks+8G
  const short* Qb = Qg + ((size_t)(n * SL + (qt << 7) + 64 * wq)) * EMB + h * HD;
  bf16x8 bQ[4][2];
#pragma unroll
  for (int nt = 0; nt < 4; ++nt)
#pragma unroll
    for (int ks = 0; ks < 2; ++ks)
      bQ[nt][ks] =
          *(const bf16x8*)(Qb + (size_t)(16 * nt + lb) * EMB + 32 * ks + 8 * G);

  f32x4 O[4][4];  // [mtd: d=16mtd+4G+r][nt: q=64wq+16nt+lb]
  float lacc[4] = {0.f, 0.f, 0.f, 0.f};
#pragma unroll
  for (int i = 0; i < 4; ++i)
#pragma unroll
    for (int j = 0; j < 4; ++j) O[i][j] = (f32x4){0.f, 0.f, 0.f, 0.f};

  // fragment-blocked bases; fold per-lane 16B chunk offset into the pointer
  const short* Kb = Kp + (((size_t)(n * NH + h)) << 17) + lane * 8;
  const short* Vb = Vp + (((size_t)(n * NH + h)) << 17) + lane * 8;

  // wave wk owns 32-key blocks kb32 = 4j + wk, j = 0..15; 2x ping-pong
  bf16x8 K0[2][2], V0[4], K1[2][2], V1[4];
  LOADK(K0, wk);
  LOADV(V0, wk);
  for (int j = 0; j < 16; j += 2) {
    const int kA = 4 * j + wk;  // even sub-round's kb32
    LOADK(K1, kA + 4);
    LOADV(V1, kA + 4);
    ATTN_STEP(K0, V0);
    if (j + 2 < 16) {
      LOADK(K0, kA + 8);
      LOADV(V0, kA + 8);
    }
    ATTN_STEP(K1, V1);
  }

  // ---- finish l: reduce across G groups (sum over this wave's keys)
#pragma unroll
  for (int nt = 0; nt < 4; ++nt) {
    lacc[nt] += __shfl_xor(lacc[nt], 16);
    lacc[nt] += __shfl_xor(lacc[nt], 32);
  }

  // ---- 4-way cross-wave reduction over wk: serial add-tree in LDS
  if (wk == 3) {
#pragma unroll
    for (int nt = 0; nt < 4; ++nt) {
      const int q = 16 * nt + lb;
#pragma unroll
      for (int mtd = 0; mtd < 4; ++mtd)
        *(f32x4*)&red[wq][q][16 * mtd + 4 * G] = O[mtd][nt];
      if (G == 0) lred[wq][q] = lacc[nt];
    }
  }
  __syncthreads();
  if (wk == 2) {
#pragma unroll
    for (int nt = 0; nt < 4; ++nt) {
      const int q = 16 * nt + lb;
#pragma unroll
      for (int mtd = 0; mtd < 4; ++mtd) {
        f32x4 t = *(const f32x4*)&red[wq][q][16 * mtd + 4 * G];
        t += O[mtd][nt];
        *(f32x4*)&red[wq][q][16 * mtd + 4 * G] = t;
      }
      if (G == 0) lred[wq][q] += lacc[nt];
    }
  }
  __syncthreads();
  if (wk == 1) {
#pragma unroll
    for (int nt = 0; nt < 4; ++nt) {
      const int q = 16 * nt + lb;
#pragma unroll
      for (int mtd = 0; mtd < 4; ++mtd) {
        f32x4 t = *(const f32x4*)&red[wq][q][16 * mtd + 4 * G];
        t += O[mtd][nt];
        *(f32x4*)&red[wq][q][16 * mtd + 4 * G] = t;
      }
      if (G == 0) lred[wq][q] += lacc[nt];
    }
  }
  __syncthreads();
  if (wk == 0) {
    short* Ao = Ab + ((size_t)(n * SL + (qt << 7) + 64 * wq)) * EMB + h * HD;
#pragma unroll
    for (int nt = 0; nt < 4; ++nt) {
      const int q = 16 * nt + lb;
      const float inv = 1.f / (lacc[nt] + lred[wq][q]);
#pragma unroll
      for (int mtd = 0; mtd < 4; ++mtd) {
        const f32x4 t = *(const f32x4*)&red[wq][q][16 * mtd + 4 * G];
        const f32x4 s = t + O[mtd][nt];
        const short4 o = {f2b(s[0] * inv), f2b(s[1] * inv), f2b(s[2] * inv),
                          f2b(s[3] * inv)};
        *(short4*)(Ao + (size_t)q * EMB + 16 * mtd + 4 * G) = o;
      }
    }
  }
}

extern "C" void kernel_launch(void* const* d_in, const int* in_sizes, int n_in,
                              void* d_out, int out_size, void* d_ws, size_t ws_size,
                              hipStream_t stream) {
  const float* x  = (const float*)d_in[0];
  const float* Wq = (const float*)d_in[1];
  const float* Wk = (const float*)d_in[2];
  const float* Wv = (const float*)d_in[3];
  const float* Wo = (const float*)d_in[4];
  const float* bo = (const float*)d_in[5];
  float* out = (float*)d_out;

  // ws (bf16 elements): xb 4M | wqkv 3M | wob 1M | qb 4M | kb 4M | vt 4M = 40 MB
  short* xb   = (short*)d_ws;
  short* wqkv = xb + PROJ;
  short* wob  = wqkv + 3u * EMB * EMB;
  short* qb   = wob + (size_t)EMB * EMB;
  short* kb   = qb + PROJ;
  short* vt   = kb + PROJ;
  short* ab   = qb;  // alias: block-disjoint read-then-write regions

  cast_all<<<8192, 256, 0, stream>>>(x, Wq, Wk, Wv, Wo, xb, wqkv, wob);
  gemm_qkv<<<dim3(24, 32), 256, 0, stream>>>(xb, wqkv, qb, kb, vt);
  attn_mfma<<<dim3(NH, SL / 128, NB), 512, 0, stream>>>(qb, kb, vt, ab);
  gemm_out<<<dim3(16, 32), 256, 0, stream>>>(ab, wob, bo, out);
}

// Round 7
// 496.936 us; speedup vs baseline: 1.0724x; 1.0724x over previous
//
#include <hip/hip_runtime.h>
#include <hip/hip_bf16.h>

constexpr int NB  = 2;
constexpr int SL  = 2048;
constexpr int EMB = 1024;
constexpr int NH  = 16;
constexpr int HD  = 64;
constexpr int MT  = NB * SL;               // 4096 rows for projection GEMMs
constexpr size_t PROJ = (size_t)MT * EMB;  // 4M elements per [N,L,E] buffer

typedef __attribute__((ext_vector_type(8))) short bf16x8;  // 8 bf16 (4 VGPRs)
typedef __attribute__((ext_vector_type(4))) float f32x4;   // MFMA C/D frag

__device__ inline short f2b(float f) {
  __hip_bfloat16 b = __float2bfloat16(f);
  short s; __builtin_memcpy(&s, &b, 2); return s;
}

#define GLDS16(g, l)                                                     \
  __builtin_amdgcn_global_load_lds(                                      \
      (const __attribute__((address_space(1))) void*)(g),                \
      (__attribute__((address_space(3))) void*)(l), 16, 0, 0)

// ---------------------------------------------------------------------------
// Cast fp32 -> bf16: x -> xb, {Wq,Wk,Wv} -> wqkv (concat rows), Wo -> wob.
// ---------------------------------------------------------------------------
__global__ __launch_bounds__(256) void cast_all(
    const float* __restrict__ x,  const float* __restrict__ wq,
    const float* __restrict__ wk, const float* __restrict__ wv,
    const float* __restrict__ wo, short* __restrict__ xb,
    short* __restrict__ wqkv, short* __restrict__ wob) {
  const size_t t = (size_t)blockIdx.x * 256 + threadIdx.x;  // float4 index
  const float* src; short* dst; size_t base;
  if (t < 1048576)      { src = x;  dst = xb;              base = 0; }
  else if (t < 1310720) { src = wq; dst = wqkv;            base = 1048576; }
  else if (t < 1572864) { src = wk; dst = wqkv + (1 << 20); base = 1310720; }
  else if (t < 1835008) { src = wv; dst = wqkv + (2 << 20); base = 1572864; }
  else                  { src = wo; dst = wob;             base = 1835008; }
  const size_t i = t - base;
  const float4 v = ((const float4*)src)[i];
  const short4 o = {f2b(v.x), f2b(v.y), f2b(v.z), f2b(v.w)};
  ((short4*)dst)[i] = o;
}

// ---------------------------------------------------------------------------
// QKV GEMM (verified): C = x[4096][1024] @ wqkv[3072][1024]^T.
// 128x128 tile, BK=64, grid 24x32 = 768 blocks (3/CU). Involutive 16B-chunk
// XOR swizzle (chunk ^= row&7): linear global_load_lds dest + inverse-
// swizzled per-lane GLOBAL source + swizzled read index (rule #21).
// Epilogue per n-region: 0 -> Q*(log2e/32) row-major; 1 -> K frag-blocked;
// 2 -> V frag-blocked (PV key-permutation folded).
// ---------------------------------------------------------------------------
__global__ __launch_bounds__(256) void gemm_qkv(
    const short* __restrict__ A, const short* __restrict__ W,
    short* __restrict__ qb, short* __restrict__ kb, short* __restrict__ vt) {
  __shared__ short As[128 * 64];
  __shared__ short Bs[128 * 64];
  const int tid = threadIdx.x;
  const int w = tid >> 6, lane = tid & 63;
  const int la = lane >> 4, lb = lane & 15;
  const int wm = w & 1, wn = w >> 1;
  const int m0 = blockIdx.y << 7, n0 = blockIdx.x << 7;
  const int srow = lane >> 3;
  const int scol = ((lane & 7) ^ srow) << 3;  // shorts
  const short* a0 = A + (size_t)(m0 + w * 32 + srow) * 1024 + scol;
  const short* b0 = W + (size_t)(n0 + w * 32 + srow) * 1024 + scol;
  short* lAw = As + (w * 32) * 64;
  short* lBw = Bs + (w * 32) * 64;

  f32x4 acc[4][4];
#pragma unroll
  for (int i = 0; i < 4; ++i)
#pragma unroll
    for (int j = 0; j < 4; ++j) acc[i][j] = (f32x4){0.f, 0.f, 0.f, 0.f};

  for (int k0 = 0; k0 < 1024; k0 += 64) {
    __syncthreads();
#pragma unroll
    for (int g = 0; g < 4; ++g) GLDS16(a0 + g * 8 * 1024 + k0, lAw + g * 8 * 64);
#pragma unroll
    for (int g = 0; g < 4; ++g) GLDS16(b0 + g * 8 * 1024 + k0, lBw + g * 8 * 64);
    __syncthreads();
#pragma unroll
    for (int ks = 0; ks < 2; ++ks) {
      bf16x8 af[4], bfr[4];
#pragma unroll
      for (int i = 0; i < 4; ++i) {
        const int row = wm * 64 + i * 16 + lb;
        af[i] = *(const bf16x8*)&As[row * 64 + (((ks << 2) + la) ^ (row & 7)) * 8];
      }
#pragma unroll
      for (int j = 0; j < 4; ++j) {
        const int row = wn * 64 + j * 16 + lb;
        bfr[j] = *(const bf16x8*)&Bs[row * 64 + (((ks << 2) + la) ^ (row & 7)) * 8];
      }
#pragma unroll
      for (int i = 0; i < 4; ++i)
#pragma unroll
        for (int j = 0; j < 4; ++j)
          acc[i][j] = __builtin_amdgcn_mfma_f32_16x16x32_bf16(af[i], bfr[j],
                                                              acc[i][j], 0, 0, 0);
    }
  }

  const int region = n0 >> 10;  // block-uniform (n-tile 128 < 1024)
  if (region == 0) {
    const float sc = 0.03125f * 1.44269504f;  // 1/sqrt(1024) * log2(e)
#pragma unroll
    for (int j = 0; j < 4; ++j) {
      const int nj = (n0 & 1023) + wn * 64 + j * 16 + lb;
#pragma unroll
      for (int i = 0; i < 4; ++i) {
        const int mi = m0 + wm * 64 + i * 16 + la * 4;
#pragma unroll
        for (int r = 0; r < 4; ++r)
          qb[(size_t)(mi + r) * 1024 + nj] = f2b(acc[i][j][r] * sc);
      }
    }
  } else if (region == 1) {
    // K fragment-blocked
#pragma unroll
    for (int j = 0; j < 4; ++j) {
      const int nj = (n0 & 1023) + wn * 64 + j * 16 + lb;
      const int hh = nj >> 6, d = nj & 63;
      const int ks = d >> 5, Gd = (d >> 3) & 3, jj = d & 7;
#pragma unroll
      for (int i = 0; i < 4; ++i) {
        const int mi = m0 + wm * 64 + i * 16 + la * 4;
        const int nbi = mi >> 11, seq = mi & (SL - 1);
        const size_t base = ((size_t)(nbi * NH + hh) << 17) +
                            (size_t)(seq >> 4) * 1024 + ks * 512 + Gd * 128 +
                            (seq & 15) * 8 + jj;
#pragma unroll
        for (int r = 0; r < 4; ++r) kb[base + r * 8] = f2b(acc[i][j][r]);
      }
    }
  } else {
    // V fragment-blocked (PV key-permutation folded in)
#pragma unroll
    for (int j = 0; j < 4; ++j) {
      const int nv = (n0 - 2048) + wn * 64 + j * 16 + lb;
      const int hh = nv >> 6, d = nv & 63;
      const int mtd = d >> 4, lbv = d & 15;
#pragma unroll
      for (int i = 0; i < 4; ++i) {
        const int mi = m0 + wm * 64 + i * 16 + la * 4;
        const int nbi = mi >> 11, seq = mi & (SL - 1);
        const int kq = seq >> 5, g = (seq >> 2) & 3, hi = (seq >> 4) & 1;
        const short4 o = {f2b(acc[i][j][0]), f2b(acc[i][j][1]),
                          f2b(acc[i][j][2]), f2b(acc[i][j][3])};
        *(short4*)&vt[((size_t)(nbi * NH + hh) << 17) + (size_t)kq * 2048 +
                      mtd * 512 + g * 128 + lbv * 8 + 4 * hi] = o;
      }
    }
  }
}

// ---------------------------------------------------------------------------
// Out GEMM (verified): out = ab[4096][1024](bf16) @ wob[1024][1024]^T + bias,
// fp32 out. 128m x 64n tile, BK=64, chunk-XOR swizzle, grid 16x32 = 512
// blocks (2/CU so barrier drains overlap).
// ---------------------------------------------------------------------------
__global__ __launch_bounds__(256) void gemm_out(
    const short* __restrict__ A, const short* __restrict__ W,
    const float* __restrict__ bias, float* __restrict__ out) {
  __shared__ short As[128 * 64];
  __shared__ short Bs[64 * 64];
  const int tid = threadIdx.x;
  const int w = tid >> 6, lane = tid & 63;
  const int la = lane >> 4, lb = lane & 15;
  const int wm = w & 1, wn = w >> 1;
  const int m0 = blockIdx.y << 7, n0 = blockIdx.x << 6;
  const int srow = lane >> 3;
  const int scol = ((lane & 7) ^ srow) << 3;
  const short* a0 = A + (size_t)(m0 + w * 32 + srow) * 1024 + scol;
  const short* b0 = W + (size_t)(n0 + w * 16 + srow) * 1024 + scol;
  short* lAw = As + (w * 32) * 64;
  short* lBw = Bs + (w * 16) * 64;

  f32x4 acc[4][2];
#pragma unroll
  for (int i = 0; i < 4; ++i)
#pragma unroll
    for (int j = 0; j < 2; ++j) acc[i][j] = (f32x4){0.f, 0.f, 0.f, 0.f};

  for (int k0 = 0; k0 < 1024; k0 += 64) {
    __syncthreads();
#pragma unroll
    for (int g = 0; g < 4; ++g) GLDS16(a0 + g * 8 * 1024 + k0, lAw + g * 8 * 64);
#pragma unroll
    for (int g = 0; g < 2; ++g) GLDS16(b0 + g * 8 * 1024 + k0, lBw + g * 8 * 64);
    __syncthreads();
#pragma unroll
    for (int ks = 0; ks < 2; ++ks) {
      bf16x8 af[4], bfr[2];
#pragma unroll
      for (int i = 0; i < 4; ++i) {
        const int row = wm * 64 + i * 16 + lb;
        af[i] = *(const bf16x8*)&As[row * 64 + (((ks << 2) + la) ^ (row & 7)) * 8];
      }
#pragma unroll
      for (int j = 0; j < 2; ++j) {
        const int row = wn * 32 + j * 16 + lb;
        bfr[j] = *(const bf16x8*)&Bs[row * 64 + (((ks << 2) + la) ^ (row & 7)) * 8];
      }
#pragma unroll
      for (int i = 0; i < 4; ++i)
#pragma unroll
        for (int j = 0; j < 2; ++j)
          acc[i][j] = __builtin_amdgcn_mfma_f32_16x16x32_bf16(af[i], bfr[j],
                                                              acc[i][j], 0, 0, 0);
    }
  }
#pragma unroll
  for (int j = 0; j < 2; ++j) {
    const int nj = n0 + wn * 32 + j * 16 + lb;
    const float bv = bias[nj];
#pragma unroll
    for (int i = 0; i < 4; ++i) {
      const int mi = m0 + wm * 64 + i * 16 + la * 4;
#pragma unroll
      for (int r = 0; r < 4; ++r)
        out[(size_t)(mi + r) * 1024 + nj] = acc[i][j][r] + bv;
    }
  }
}

// ---------------------------------------------------------------------------
// Flash attention v11: v9's zero-LDS loop at 2x occupancy via GRID (not
// block shape — R6's (512,4) spilled to 64 VGPR; reverted).
//  * 64 q-rows per block, grid (16, 32, 2) = 1024 blocks x 256 threads.
//    4 waves = 4-way key split: wave wk owns kb32 blocks {4j+wk}, 512 keys.
//    1024 blocks x 4 waves = 4096 waves = 4/SIMD (was 2) at 128 VGPR.
//  * Per-wave register state IDENTICAL to v9 (bQ 32 + O 64 + K/V pp 64
//    ~ 128 VGPR); __launch_bounds__(256,4) sets exactly that budget.
//  * L2 traffic unchanged: block reads full 512 KB K/V slice once; 32
//    blocks/slice; id%8 == h%8 keeps slice-sharing blocks on one XCD.
//  * Epilogue: 4-way serial LDS add-tree over wk (verified in R6).
// ---------------------------------------------------------------------------
#define LOADK(DK, KB32)                                                      \
  do {                                                                       \
    _Pragma("unroll") for (int rr_ = 0; rr_ < 2; ++rr_)                      \
        _Pragma("unroll") for (int ks_ = 0; ks_ < 2; ++ks_)                  \
            DK[rr_][ks_] = *(const bf16x8*)(Kb + (size_t)(KB32) * 2048 +     \
                                            rr_ * 1024 + ks_ * 512);         \
  } while (0)

#define LOADV(DV, KB32)                                                      \
  do {                                                                       \
    _Pragma("unroll") for (int md_ = 0; md_ < 4; ++md_)                      \
        DV[md_] = *(const bf16x8*)(Vb + (size_t)(KB32) * 2048 + md_ * 512);  \
  } while (0)

#define ATTN_STEP(AK, AV)                                                    \
  do {                                                                       \
    f32x4 S[2][4];                                                           \
    _Pragma("unroll") for (int mt = 0; mt < 2; ++mt)                         \
        _Pragma("unroll") for (int nt = 0; nt < 4; ++nt)                     \
            S[mt][nt] = (f32x4){0.f, 0.f, 0.f, 0.f};                         \
    __builtin_amdgcn_s_setprio(1);                                           \
    _Pragma("unroll") for (int ks = 0; ks < 2; ++ks)                         \
        _Pragma("unroll") for (int nt = 0; nt < 4; ++nt) {                   \
      S[0][nt] = __builtin_amdgcn_mfma_f32_16x16x32_bf16(AK[0][ks],          \
                     bQ[nt][ks], S[0][nt], 0, 0, 0);                         \
      S[1][nt] = __builtin_amdgcn_mfma_f32_16x16x32_bf16(AK[1][ks],          \
                     bQ[nt][ks], S[1][nt], 0, 0, 0);                         \
    }                                                                        \
    __builtin_amdgcn_s_setprio(0);                                           \
    _Pragma("unroll") for (int nt = 0; nt < 4; ++nt) {                       \
      _Pragma("unroll") for (int mt = 0; mt < 2; ++mt)                       \
          _Pragma("unroll") for (int r = 0; r < 4; ++r) {                    \
        const float p = __builtin_amdgcn_exp2f(S[mt][nt][r]);                \
        S[mt][nt][r] = p;                                                    \
        lacc[nt] += p;                                                       \
      }                                                                      \
      bf16x8 B2;                                                             \
      B2[0] = f2b(S[0][nt][0]); B2[1] = f2b(S[0][nt][1]);                    \
      B2[2] = f2b(S[0][nt][2]); B2[3] = f2b(S[0][nt][3]);                    \
      B2[4] = f2b(S[1][nt][0]); B2[5] = f2b(S[1][nt][1]);                    \
      B2[6] = f2b(S[1][nt][2]); B2[7] = f2b(S[1][nt][3]);                    \
      __builtin_amdgcn_s_setprio(1);                                         \
      _Pragma("unroll") for (int mtd = 0; mtd < 4; ++mtd)                    \
          O[mtd][nt] = __builtin_amdgcn_mfma_f32_16x16x32_bf16(              \
              AV[mtd], B2, O[mtd][nt], 0, 0, 0);                             \
      __builtin_amdgcn_s_setprio(0);                                         \
    }                                                                        \
  } while (0)

__global__ __launch_bounds__(256, 4) void attn_mfma(const short* __restrict__ Qg,
                                                    const short* __restrict__ Kp,
                                                    const short* __restrict__ Vp,
                                                    short* __restrict__ Ab) {
  __shared__ __align__(16) float red[64][68];  // 17408 B
  __shared__ float lred[64];
  const int tid = threadIdx.x;
  const int wk = tid >> 6, lane = tid & 63;
  const int G = lane >> 4, lb = lane & 15;
  const int h = blockIdx.x, qt = blockIdx.y, n = blockIdx.z;

  // ---- Q fragments: global -> regs, once. q = 16nt+lb, d = 32ks+8G
  const short* Qb = Qg + ((size_t)(n * SL + (qt << 6))) * EMB + h * HD;
  bf16x8 bQ[4][2];
#pragma unroll
  for (int nt = 0; nt < 4; ++nt)
#pragma unroll
    for (int ks = 0; ks < 2; ++ks)
      bQ[nt][ks] =
          *(const bf16x8*)(Qb + (size_t)(16 * nt + lb) * EMB + 32 * ks + 8 * G);

  f32x4 O[4][4];  // [mtd: d=16mtd+4G+r][nt: q=16nt+lb]
  float lacc[4] = {0.f, 0.f, 0.f, 0.f};
#pragma unroll
  for (int i = 0; i < 4; ++i)
#pragma unroll
    for (int j = 0; j < 4; ++j) O[i][j] = (f32x4){0.f, 0.f, 0.f, 0.f};

  // fragment-blocked bases; fold per-lane 16B chunk offset into the pointer
  const short* Kb = Kp + (((size_t)(n * NH + h)) << 17) + lane * 8;
  const short* Vb = Vp + (((size_t)(n * NH + h)) << 17) + lane * 8;

  // wave wk owns 32-key blocks kb32 = 4j + wk, j = 0..15; 2x ping-pong
  bf16x8 K0[2][2], V0[4], K1[2][2], V1[4];
  LOADK(K0, wk);
  LOADV(V0, wk);
  for (int j = 0; j < 16; j += 2) {
    const int kA = 4 * j + wk;  // even sub-round's kb32
    LOADK(K1, kA + 4);
    LOADV(V1, kA + 4);
    ATTN_STEP(K0, V0);
    if (j + 2 < 16) {
      LOADK(K0, kA + 8);
      LOADV(V0, kA + 8);
    }
    ATTN_STEP(K1, V1);
  }

  // ---- finish l: reduce across G groups (sum over this wave's keys)
#pragma unroll
  for (int nt = 0; nt < 4; ++nt) {
    lacc[nt] += __shfl_xor(lacc[nt], 16);
    lacc[nt] += __shfl_xor(lacc[nt], 32);
  }

  // ---- 4-way cross-wave reduction over wk: serial add-tree in LDS
  if (wk == 3) {
#pragma unroll
    for (int nt = 0; nt < 4; ++nt) {
      const int q = 16 * nt + lb;
#pragma unroll
      for (int mtd = 0; mtd < 4; ++mtd)
        *(f32x4*)&red[q][16 * mtd + 4 * G] = O[mtd][nt];
      if (G == 0) lred[q] = lacc[nt];
    }
  }
  __syncthreads();
  if (wk == 2) {
#pragma unroll
    for (int nt = 0; nt < 4; ++nt) {
      const int q = 16 * nt + lb;
#pragma unroll
      for (int mtd = 0; mtd < 4; ++mtd) {
        f32x4 t = *(const f32x4*)&red[q][16 * mtd + 4 * G];
        t += O[mtd][nt];
        *(f32x4*)&red[q][16 * mtd + 4 * G] = t;
      }
      if (G == 0) lred[q] += lacc[nt];
    }
  }
  __syncthreads();
  if (wk == 1) {
#pragma unroll
    for (int nt = 0; nt < 4; ++nt) {
      const int q = 16 * nt + lb;
#pragma unroll
      for (int mtd = 0; mtd < 4; ++mtd) {
        f32x4 t = *(const f32x4*)&red[q][16 * mtd + 4 * G];
        t += O[mtd][nt];
        *(f32x4*)&red[q][16 * mtd + 4 * G] = t;
      }
      if (G == 0) lred[q] += lacc[nt];
    }
  }
  __syncthreads();
  if (wk == 0) {
    short* Ao = Ab + ((size_t)(n * SL + (qt << 6))) * EMB + h * HD;
#pragma unroll
    for (int nt = 0; nt < 4; ++nt) {
      const int q = 16 * nt + lb;
      const float inv = 1.f / (lacc[nt] + lred[q]);
#pragma unroll
      for (int mtd = 0; mtd < 4; ++mtd) {
        const f32x4 t = *(const f32x4*)&red[q][16 * mtd + 4 * G];
        const f32x4 s = t + O[mtd][nt];
        const short4 o = {f2b(s[0] * inv), f2b(s[1] * inv), f2b(s[2] * inv),
                          f2b(s[3] * inv)};
        *(short4*)(Ao + (size_t)q * EMB + 16 * mtd + 4 * G) = o;
      }
    }
  }
}

extern "C" void kernel_launch(void* const* d_in, const int* in_sizes, int n_in,
                              void* d_out, int out_size, void* d_ws, size_t ws_size,
                              hipStream_t stream) {
  const float* x  = (const float*)d_in[0];
  const float* Wq = (const float*)d_in[1];
  const float* Wk = (const float*)d_in[2];
  const float* Wv = (const float*)d_in[3];
  const float* Wo = (const float*)d_in[4];
  const float* bo = (const float*)d_in[5];
  float* out = (float*)d_out;

  // ws (bf16 elements): xb 4M | wqkv 3M | wob 1M | qb 4M | kb 4M | vt 4M = 40 MB
  short* xb   = (short*)d_ws;
  short* wqkv = xb + PROJ;
  short* wob  = wqkv + 3u * EMB * EMB;
  short* qb   = wob + (size_t)EMB * EMB;
  short* kb   = qb + PROJ;
  short* vt   = kb + PROJ;
  short* ab   = qb;  // alias: block-disjoint read-then-write regions

  cast_all<<<8192, 256, 0, stream>>>(x, Wq, Wk, Wv, Wo, xb, wqkv, wob);
  gemm_qkv<<<dim3(24, 32), 256, 0, stream>>>(xb, wqkv, qb, kb, vt);
  attn_mfma<<<dim3(NH, SL / 64, NB), 256, 0, stream>>>(qb, kb, vt, ab);
  gemm_out<<<dim3(16, 32), 256, 0, stream>>>(ab, wob, bo, out);
}

// Round 8
// 178.747 us; speedup vs baseline: 2.9814x; 2.7801x over previous
//
#include <hip/hip_runtime.h>
#include <hip/hip_bf16.h>

constexpr int NB  = 2;
constexpr int SL  = 2048;
constexpr int EMB = 1024;
constexpr int NH  = 16;
constexpr int HD  = 64;
constexpr int MT  = NB * SL;               // 4096 rows for projection GEMMs
constexpr size_t PROJ = (size_t)MT * EMB;  // 4M elements per [N,L,E] buffer

typedef __attribute__((ext_vector_type(8))) short bf16x8;  // 8 bf16 (4 VGPRs)
typedef __attribute__((ext_vector_type(4))) float f32x4;   // MFMA C/D frag

__device__ inline short f2b(float f) {
  __hip_bfloat16 b = __float2bfloat16(f);
  short s; __builtin_memcpy(&s, &b, 2); return s;
}

#define GLDS16(g, l)                                                     \
  __builtin_amdgcn_global_load_lds(                                      \
      (const __attribute__((address_space(1))) void*)(g),                \
      (__attribute__((address_space(3))) void*)(l), 16, 0, 0)

// ---------------------------------------------------------------------------
// Cast fp32 -> bf16: x -> xb, {Wq,Wk,Wv} -> wqkv (concat rows), Wo -> wob.
// ---------------------------------------------------------------------------
__global__ __launch_bounds__(256) void cast_all(
    const float* __restrict__ x,  const float* __restrict__ wq,
    const float* __restrict__ wk, const float* __restrict__ wv,
    const float* __restrict__ wo, short* __restrict__ xb,
    short* __restrict__ wqkv, short* __restrict__ wob) {
  const size_t t = (size_t)blockIdx.x * 256 + threadIdx.x;  // float4 index
  const float* src; short* dst; size_t base;
  if (t < 1048576)      { src = x;  dst = xb;              base = 0; }
  else if (t < 1310720) { src = wq; dst = wqkv;            base = 1048576; }
  else if (t < 1572864) { src = wk; dst = wqkv + (1 << 20); base = 1310720; }
  else if (t < 1835008) { src = wv; dst = wqkv + (2 << 20); base = 1572864; }
  else                  { src = wo; dst = wob;             base = 1835008; }
  const size_t i = t - base;
  const float4 v = ((const float4*)src)[i];
  const short4 o = {f2b(v.x), f2b(v.y), f2b(v.z), f2b(v.w)};
  ((short4*)dst)[i] = o;
}

// ---------------------------------------------------------------------------
// QKV GEMM (verified): C = x[4096][1024] @ wqkv[3072][1024]^T.
// 128x128 tile, BK=64, grid 24x32 = 768 blocks (3/CU). Involutive 16B-chunk
// XOR swizzle (chunk ^= row&7): linear global_load_lds dest + inverse-
// swizzled per-lane GLOBAL source + swizzled read index (rule #21).
// Epilogue per n-region: 0 -> Q*(log2e/32) row-major; 1 -> K frag-blocked;
// 2 -> V frag-blocked (PV key-permutation folded).
// ---------------------------------------------------------------------------
__global__ __launch_bounds__(256) void gemm_qkv(
    const short* __restrict__ A, const short* __restrict__ W,
    short* __restrict__ qb, short* __restrict__ kb, short* __restrict__ vt) {
  __shared__ short As[128 * 64];
  __shared__ short Bs[128 * 64];
  const int tid = threadIdx.x;
  const int w = tid >> 6, lane = tid & 63;
  const int la = lane >> 4, lb = lane & 15;
  const int wm = w & 1, wn = w >> 1;
  const int m0 = blockIdx.y << 7, n0 = blockIdx.x << 7;
  const int srow = lane >> 3;
  const int scol = ((lane & 7) ^ srow) << 3;  // shorts
  const short* a0 = A + (size_t)(m0 + w * 32 + srow) * 1024 + scol;
  const short* b0 = W + (size_t)(n0 + w * 32 + srow) * 1024 + scol;
  short* lAw = As + (w * 32) * 64;
  short* lBw = Bs + (w * 32) * 64;

  f32x4 acc[4][4];
#pragma unroll
  for (int i = 0; i < 4; ++i)
#pragma unroll
    for (int j = 0; j < 4; ++j) acc[i][j] = (f32x4){0.f, 0.f, 0.f, 0.f};

  for (int k0 = 0; k0 < 1024; k0 += 64) {
    __syncthreads();
#pragma unroll
    for (int g = 0; g < 4; ++g) GLDS16(a0 + g * 8 * 1024 + k0, lAw + g * 8 * 64);
#pragma unroll
    for (int g = 0; g < 4; ++g) GLDS16(b0 + g * 8 * 1024 + k0, lBw + g * 8 * 64);
    __syncthreads();
#pragma unroll
    for (int ks = 0; ks < 2; ++ks) {
      bf16x8 af[4], bfr[4];
#pragma unroll
      for (int i = 0; i < 4; ++i) {
        const int row = wm * 64 + i * 16 + lb;
        af[i] = *(const bf16x8*)&As[row * 64 + (((ks << 2) + la) ^ (row & 7)) * 8];
      }
#pragma unroll
      for (int j = 0; j < 4; ++j) {
        const int row = wn * 64 + j * 16 + lb;
        bfr[j] = *(const bf16x8*)&Bs[row * 64 + (((ks << 2) + la) ^ (row & 7)) * 8];
      }
#pragma unroll
      for (int i = 0; i < 4; ++i)
#pragma unroll
        for (int j = 0; j < 4; ++j)
          acc[i][j] = __builtin_amdgcn_mfma_f32_16x16x32_bf16(af[i], bfr[j],
                                                              acc[i][j], 0, 0, 0);
    }
  }

  const int region = n0 >> 10;  // block-uniform (n-tile 128 < 1024)
  if (region == 0) {
    const float sc = 0.03125f * 1.44269504f;  // 1/sqrt(1024) * log2(e)
#pragma unroll
    for (int j = 0; j < 4; ++j) {
      const int nj = (n0 & 1023) + wn * 64 + j * 16 + lb;
#pragma unroll
      for (int i = 0; i < 4; ++i) {
        const int mi = m0 + wm * 64 + i * 16 + la * 4;
#pragma unroll
        for (int r = 0; r < 4; ++r)
          qb[(size_t)(mi + r) * 1024 + nj] = f2b(acc[i][j][r] * sc);
      }
    }
  } else if (region == 1) {
    // K fragment-blocked
#pragma unroll
    for (int j = 0; j < 4; ++j) {
      const int nj = (n0 & 1023) + wn * 64 + j * 16 + lb;
      const int hh = nj >> 6, d = nj & 63;
      const int ks = d >> 5, Gd = (d >> 3) & 3, jj = d & 7;
#pragma unroll
      for (int i = 0; i < 4; ++i) {
        const int mi = m0 + wm * 64 + i * 16 + la * 4;
        const int nbi = mi >> 11, seq = mi & (SL - 1);
        const size_t base = ((size_t)(nbi * NH + hh) << 17) +
                            (size_t)(seq >> 4) * 1024 + ks * 512 + Gd * 128 +
                            (seq & 15) * 8 + jj;
#pragma unroll
        for (int r = 0; r < 4; ++r) kb[base + r * 8] = f2b(acc[i][j][r]);
      }
    }
  } else {
    // V fragment-blocked (PV key-permutation folded in)
#pragma unroll
    for (int j = 0; j < 4; ++j) {
      const int nv = (n0 - 2048) + wn * 64 + j * 16 + lb;
      const int hh = nv >> 6, d = nv & 63;
      const int mtd = d >> 4, lbv = d & 15;
#pragma unroll
      for (int i = 0; i < 4; ++i) {
        const int mi = m0 + wm * 64 + i * 16 + la * 4;
        const int nbi = mi >> 11, seq = mi & (SL - 1);
        const int kq = seq >> 5, g = (seq >> 2) & 3, hi = (seq >> 4) & 1;
        const short4 o = {f2b(acc[i][j][0]), f2b(acc[i][j][1]),
                          f2b(acc[i][j][2]), f2b(acc[i][j][3])};
        *(short4*)&vt[((size_t)(nbi * NH + hh) << 17) + (size_t)kq * 2048 +
                      mtd * 512 + g * 128 + lbv * 8 + 4 * hi] = o;
      }
    }
  }
}

// ---------------------------------------------------------------------------
// Out GEMM (verified): out = ab[4096][1024](bf16) @ wob[1024][1024]^T + bias,
// fp32 out. 128m x 64n tile, BK=64, chunk-XOR swizzle, grid 16x32 = 512
// blocks (2/CU so barrier drains overlap).
// ---------------------------------------------------------------------------
__global__ __launch_bounds__(256) void gemm_out(
    const short* __restrict__ A, const short* __restrict__ W,
    const float* __restrict__ bias, float* __restrict__ out) {
  __shared__ short As[128 * 64];
  __shared__ short Bs[64 * 64];
  const int tid = threadIdx.x;
  const int w = tid >> 6, lane = tid & 63;
  const int la = lane >> 4, lb = lane & 15;
  const int wm = w & 1, wn = w >> 1;
  const int m0 = blockIdx.y << 7, n0 = blockIdx.x << 6;
  const int srow = lane >> 3;
  const int scol = ((lane & 7) ^ srow) << 3;
  const short* a0 = A + (size_t)(m0 + w * 32 + srow) * 1024 + scol;
  const short* b0 = W + (size_t)(n0 + w * 16 + srow) * 1024 + scol;
  short* lAw = As + (w * 32) * 64;
  short* lBw = Bs + (w * 16) * 64;

  f32x4 acc[4][2];
#pragma unroll
  for (int i = 0; i < 4; ++i)
#pragma unroll
    for (int j = 0; j < 2; ++j) acc[i][j] = (f32x4){0.f, 0.f, 0.f, 0.f};

  for (int k0 = 0; k0 < 1024; k0 += 64) {
    __syncthreads();
#pragma unroll
    for (int g = 0; g < 4; ++g) GLDS16(a0 + g * 8 * 1024 + k0, lAw + g * 8 * 64);
#pragma unroll
    for (int g = 0; g < 2; ++g) GLDS16(b0 + g * 8 * 1024 + k0, lBw + g * 8 * 64);
    __syncthreads();
#pragma unroll
    for (int ks = 0; ks < 2; ++ks) {
      bf16x8 af[4], bfr[2];
#pragma unroll
      for (int i = 0; i < 4; ++i) {
        const int row = wm * 64 + i * 16 + lb;
        af[i] = *(const bf16x8*)&As[row * 64 + (((ks << 2) + la) ^ (row & 7)) * 8];
      }
#pragma unroll
      for (int j = 0; j < 2; ++j) {
        const int row = wn * 32 + j * 16 + lb;
        bfr[j] = *(const bf16x8*)&Bs[row * 64 + (((ks << 2) + la) ^ (row & 7)) * 8];
      }
#pragma unroll
      for (int i = 0; i < 4; ++i)
#pragma unroll
        for (int j = 0; j < 2; ++j)
          acc[i][j] = __builtin_amdgcn_mfma_f32_16x16x32_bf16(af[i], bfr[j],
                                                              acc[i][j], 0, 0, 0);
    }
  }
#pragma unroll
  for (int j = 0; j < 2; ++j) {
    const int nj = n0 + wn * 32 + j * 16 + lb;
    const float bv = bias[nj];
#pragma unroll
    for (int i = 0; i < 4; ++i) {
      const int mi = m0 + wm * 64 + i * 16 + la * 4;
#pragma unroll
      for (int r = 0; r < 4; ++r)
        out[(size_t)(mi + r) * 1024 + nj] = acc[i][j][r] + bv;
    }
  }
}

// ---------------------------------------------------------------------------
// Flash attention v12 = R7's v11 with the launch_bounds fix.
//  * Empirical toolchain rule (two data points, R6/R7): VGPR cap =
//    256/min_waves. (256,4)/(512,4) -> 64 VGPR -> ~160-reg working set
//    spills (FETCH 673 MB, 366 us). (256,2) -> 128 VGPR, no spill (v9).
//  * HW occupancy at 128 VGPR already permits 4 waves/SIMD (waves halve at
//    64/128/256); the grid supplies them: 1024 blocks x 4 waves = 4096
//    waves = 4/SIMD, double v9.
//  * Structure: 64 q-rows/block, grid (16,32,2); 4 waves = 4-way key split
//    (wave wk owns kb32 {4j+wk}); zero-LDS main loop, direct global->reg
//    fragment-blocked K/V; 4-way serial LDS add-tree epilogue.
// ---------------------------------------------------------------------------
#define LOADK(DK, KB32)                                                      \
  do {                                                                       \
    _Pragma("unroll") for (int rr_ = 0; rr_ < 2; ++rr_)                      \
        _Pragma("unroll") for (int ks_ = 0; ks_ < 2; ++ks_)                  \
            DK[rr_][ks_] = *(const bf16x8*)(Kb + (size_t)(KB32) * 2048 +     \
                                            rr_ * 1024 + ks_ * 512);         \
  } while (0)

#define LOADV(DV, KB32)                                                      \
  do {                                                                       \
    _Pragma("unroll") for (int md_ = 0; md_ < 4; ++md_)                      \
        DV[md_] = *(const bf16x8*)(Vb + (size_t)(KB32) * 2048 + md_ * 512);  \
  } while (0)

#define ATTN_STEP(AK, AV)                                                    \
  do {                                                                       \
    f32x4 S[2][4];                                                           \
    _Pragma("unroll") for (int mt = 0; mt < 2; ++mt)                         \
        _Pragma("unroll") for (int nt = 0; nt < 4; ++nt)                     \
            S[mt][nt] = (f32x4){0.f, 0.f, 0.f, 0.f};                         \
    __builtin_amdgcn_s_setprio(1);                                           \
    _Pragma("unroll") for (int ks = 0; ks < 2; ++ks)                         \
        _Pragma("unroll") for (int nt = 0; nt < 4; ++nt) {                   \
      S[0][nt] = __builtin_amdgcn_mfma_f32_16x16x32_bf16(AK[0][ks],          \
                     bQ[nt][ks], S[0][nt], 0, 0, 0);                         \
      S[1][nt] = __builtin_amdgcn_mfma_f32_16x16x32_bf16(AK[1][ks],          \
                     bQ[nt][ks], S[1][nt], 0, 0, 0);                         \
    }                                                                        \
    __builtin_amdgcn_s_setprio(0);                                           \
    _Pragma("unroll") for (int nt = 0; nt < 4; ++nt) {                       \
      _Pragma("unroll") for (int mt = 0; mt < 2; ++mt)                       \
          _Pragma("unroll") for (int r = 0; r < 4; ++r) {                    \
        const float p = __builtin_amdgcn_exp2f(S[mt][nt][r]);                \
        S[mt][nt][r] = p;                                                    \
        lacc[nt] += p;                                                       \
      }                                                                      \
      bf16x8 B2;                                                             \
      B2[0] = f2b(S[0][nt][0]); B2[1] = f2b(S[0][nt][1]);                    \
      B2[2] = f2b(S[0][nt][2]); B2[3] = f2b(S[0][nt][3]);                    \
      B2[4] = f2b(S[1][nt][0]); B2[5] = f2b(S[1][nt][1]);                    \
      B2[6] = f2b(S[1][nt][2]); B2[7] = f2b(S[1][nt][3]);                    \
      __builtin_amdgcn_s_setprio(1);                                         \
      _Pragma("unroll") for (int mtd = 0; mtd < 4; ++mtd)                    \
          O[mtd][nt] = __builtin_amdgcn_mfma_f32_16x16x32_bf16(              \
              AV[mtd], B2, O[mtd][nt], 0, 0, 0);                             \
      __builtin_amdgcn_s_setprio(0);                                         \
    }                                                                        \
  } while (0)

__global__ __launch_bounds__(256, 2) void attn_mfma(const short* __restrict__ Qg,
                                                    const short* __restrict__ Kp,
                                                    const short* __restrict__ Vp,
                                                    short* __restrict__ Ab) {
  __shared__ __align__(16) float red[64][68];  // 17408 B
  __shared__ float lred[64];
  const int tid = threadIdx.x;
  const int wk = tid >> 6, lane = tid & 63;
  const int G = lane >> 4, lb = lane & 15;
  const int h = blockIdx.x, qt = blockIdx.y, n = blockIdx.z;

  // ---- Q fragments: global -> regs, once. q = 16nt+lb, d = 32ks+8G
  const short* Qb = Qg + ((size_t)(n * SL + (qt << 6))) * EMB + h * HD;
  bf16x8 bQ[4][2];
#pragma unroll
  for (int nt = 0; nt < 4; ++nt)
#pragma unroll
    for (int ks = 0; ks < 2; ++ks)
      bQ[nt][ks] =
          *(const bf16x8*)(Qb + (size_t)(16 * nt + lb) * EMB + 32 * ks + 8 * G);

  f32x4 O[4][4];  // [mtd: d=16mtd+4G+r][nt: q=16nt+lb]
  float lacc[4] = {0.f, 0.f, 0.f, 0.f};
#pragma unroll
  for (int i = 0; i < 4; ++i)
#pragma unroll
    for (int j = 0; j < 4; ++j) O[i][j] = (f32x4){0.f, 0.f, 0.f, 0.f};

  // fragment-blocked bases; fold per-lane 16B chunk offset into the pointer
  const short* Kb = Kp + (((size_t)(n * NH + h)) << 17) + lane * 8;
  const short* Vb = Vp + (((size_t)(n * NH + h)) << 17) + lane * 8;

  // wave wk owns 32-key blocks kb32 = 4j + wk, j = 0..15; 2x ping-pong
  bf16x8 K0[2][2], V0[4], K1[2][2], V1[4];
  LOADK(K0, wk);
  LOADV(V0, wk);
  for (int j = 0; j < 16; j += 2) {
    const int kA = 4 * j + wk;  // even sub-round's kb32
    LOADK(K1, kA + 4);
    LOADV(V1, kA + 4);
    ATTN_STEP(K0, V0);
    if (j + 2 < 16) {
      LOADK(K0, kA + 8);
      LOADV(V0, kA + 8);
    }
    ATTN_STEP(K1, V1);
  }

  // ---- finish l: reduce across G groups (sum over this wave's keys)
#pragma unroll
  for (int nt = 0; nt < 4; ++nt) {
    lacc[nt] += __shfl_xor(lacc[nt], 16);
    lacc[nt] += __shfl_xor(lacc[nt], 32);
  }

  // ---- 4-way cross-wave reduction over wk: serial add-tree in LDS
  if (wk == 3) {
#pragma unroll
    for (int nt = 0; nt < 4; ++nt) {
      const int q = 16 * nt + lb;
#pragma unroll
      for (int mtd = 0; mtd < 4; ++mtd)
        *(f32x4*)&red[q][16 * mtd + 4 * G] = O[mtd][nt];
      if (G == 0) lred[q] = lacc[nt];
    }
  }
  __syncthreads();
  if (wk == 2) {
#pragma unroll
    for (int nt = 0; nt < 4; ++nt) {
      const int q = 16 * nt + lb;
#pragma unroll
      for (int mtd = 0; mtd < 4; ++mtd) {
        f32x4 t = *(const f32x4*)&red[q][16 * mtd + 4 * G];
        t += O[mtd][nt];
        *(f32x4*)&red[q][16 * mtd + 4 * G] = t;
      }
      if (G == 0) lred[q] += lacc[nt];
    }
  }
  __syncthreads();
  if (wk == 1) {
#pragma unroll
    for (int nt = 0; nt < 4; ++nt) {
      const int q = 16 * nt + lb;
#pragma unroll
      for (int mtd = 0; mtd < 4; ++mtd) {
        f32x4 t = *(const f32x4*)&red[q][16 * mtd + 4 * G];
        t += O[mtd][nt];
        *(f32x4*)&red[q][16 * mtd + 4 * G] = t;
      }
      if (G == 0) lred[q] += lacc[nt];
    }
  }
  __syncthreads();
  if (wk == 0) {
    short* Ao = Ab + ((size_t)(n * SL + (qt << 6))) * EMB + h * HD;
#pragma unroll
    for (int nt = 0; nt < 4; ++nt) {
      const int q = 16 * nt + lb;
      const float inv = 1.f / (lacc[nt] + lred[q]);
#pragma unroll
      for (int mtd = 0; mtd < 4; ++mtd) {
        const f32x4 t = *(const f32x4*)&red[q][16 * mtd + 4 * G];
        const f32x4 s = t + O[mtd][nt];
        const short4 o = {f2b(s[0] * inv), f2b(s[1] * inv), f2b(s[2] * inv),
                          f2b(s[3] * inv)};
        *(short4*)(Ao + (size_t)q * EMB + 16 * mtd + 4 * G) = o;
      }
    }
  }
}

extern "C" void kernel_launch(void* const* d_in, const int* in_sizes, int n_in,
                              void* d_out, int out_size, void* d_ws, size_t ws_size,
                              hipStream_t stream) {
  const float* x  = (const float*)d_in[0];
  const float* Wq = (const float*)d_in[1];
  const float* Wk = (const float*)d_in[2];
  const float* Wv = (const float*)d_in[3];
  const float* Wo = (const float*)d_in[4];
  const float* bo = (const float*)d_in[5];
  float* out = (float*)d_out;

  // ws (bf16 elements): xb 4M | wqkv 3M | wob 1M | qb 4M | kb 4M | vt 4M = 40 MB
  short* xb   = (short*)d_ws;
  short* wqkv = xb + PROJ;
  short* wob  = wqkv + 3u * EMB * EMB;
  short* qb   = wob + (size_t)EMB * EMB;
  short* kb   = qb + PROJ;
  short* vt   = kb + PROJ;
  short* ab   = qb;  // alias: block-disjoint read-then-write regions

  cast_all<<<8192, 256, 0, stream>>>(x, Wq, Wk, Wv, Wo, xb, wqkv, wob);
  gemm_qkv<<<dim3(24, 32), 256, 0, stream>>>(xb, wqkv, qb, kb, vt);
  attn_mfma<<<dim3(NH, SL / 64, NB), 256, 0, stream>>>(qb, kb, vt, ab);
  gemm_out<<<dim3(16, 32), 256, 0, stream>>>(ab, wob, bo, out);
}